// Round 2
// baseline (488.214 us; speedup 1.0000x reference)
//
#include <hip/hip_runtime.h>

#define N_PTS 16384
#define NH 16
#define NC 192
#define NK 43
#define ND 2
#define BN_EPS 1e-5f

// ---------- copy feat -> X working buffer ----------
__global__ void k_copy(const float* __restrict__ in, float* __restrict__ out, int n) {
    int i = blockIdx.x * blockDim.x + threadIdx.x;
    int stride = gridDim.x * blockDim.x;
    for (; i < n; i += stride) out[i] = in[i];
}

// ---------- [N,C] x [C,C] GEMM: Out = X @ W ----------
// block = 192 threads (one column per thread), 16 rows per block staged in LDS.
__global__ __launch_bounds__(192) void k_gemm(const float* __restrict__ X,
                                              const float* __restrict__ W,
                                              float* __restrict__ Out) {
    __shared__ __align__(16) float Xs[16 * NC];
    const int c = threadIdx.x;
    const int r0 = blockIdx.x * 16;
    const float* src = X + r0 * NC;
    for (int t = c; t < 16 * NC; t += NC) Xs[t] = src[t];  // tile is contiguous span
    __syncthreads();

    float acc[16];
#pragma unroll
    for (int r = 0; r < 16; ++r) acc[r] = 0.f;

    for (int k4 = 0; k4 < NC / 4; ++k4) {
        float w0 = W[(4 * k4 + 0) * NC + c];
        float w1 = W[(4 * k4 + 1) * NC + c];
        float w2 = W[(4 * k4 + 2) * NC + c];
        float w3 = W[(4 * k4 + 3) * NC + c];
#pragma unroll
        for (int r = 0; r < 16; ++r) {
            float4 xv = *(const float4*)(Xs + r * NC + 4 * k4);  // LDS broadcast
            acc[r] = fmaf(xv.x, w0, acc[r]);
            acc[r] = fmaf(xv.y, w1, acc[r]);
            acc[r] = fmaf(xv.z, w2, acc[r]);
            acc[r] = fmaf(xv.w, w3, acc[r]);
        }
    }
    float* dst = Out + r0 * NC + c;
#pragma unroll
    for (int r = 0; r < 16; ++r) dst[r * NC] = acc[r];
}

// ---------- BN stats stage 1: 64 blocks x 256 rows, per-channel partial sums ----------
__global__ __launch_bounds__(192) void k_stat1(const float* __restrict__ A,
                                               float* __restrict__ part) {
    const int c = threadIdx.x;
    const int b = blockIdx.x;
    const float* p = A + b * 256 * NC + c;
    float s = 0.f, sq = 0.f;
    for (int r = 0; r < 256; ++r) {
        float v = p[r * NC];
        s += v;
        sq = fmaf(v, v, sq);
    }
    part[b * (2 * NC) + c] = s;
    part[b * (2 * NC) + NC + c] = sq;
}

// ---------- BN stats stage 2: finalize mean / rstd ----------
__global__ __launch_bounds__(192) void k_stat2(const float* __restrict__ part,
                                               float* __restrict__ stats) {
    const int c = threadIdx.x;
    float s = 0.f, sq = 0.f;
    for (int b = 0; b < 64; ++b) {
        s += part[b * (2 * NC) + c];
        sq += part[b * (2 * NC) + NC + c];
    }
    float m = s * (1.f / N_PTS);
    float var = sq * (1.f / N_PTS) - m * m;   // population var, matches jnp.var
    stats[c] = m;
    stats[NC + c] = rsqrtf(var + BN_EPS);
}

// ---------- BN apply + ReLU (in place) ----------
__global__ __launch_bounds__(192) void k_bn_relu(float* __restrict__ A,
                                                 const float* __restrict__ stats,
                                                 const float* __restrict__ g,
                                                 const float* __restrict__ b) {
    const int c = threadIdx.x;
    const float m = stats[c], rs = stats[NC + c];
    const float gg = g[c], bb = b[c];
    const int base = blockIdx.x * 8;
#pragma unroll
    for (int r = 0; r < 8; ++r) {
        int i = (base + r) * NC + c;
        float v = (A[i] - m) * rs * gg + bb;
        A[i] = fmaxf(v, 0.f);
    }
}

// ---------- BN apply + skip + ReLU; optionally emit final output ----------
__global__ __launch_bounds__(192) void k_bn_skip(const float* __restrict__ Tt,
                                                 const float* __restrict__ stats,
                                                 const float* __restrict__ g,
                                                 const float* __restrict__ b,
                                                 float* __restrict__ X,
                                                 float* __restrict__ out) {
    const int c = threadIdx.x;
    const float m = stats[c], rs = stats[NC + c];
    const float gg = g[c], bb = b[c];
    const int base = blockIdx.x * 8;
#pragma unroll
    for (int r = 0; r < 8; ++r) {
        int i = (base + r) * NC + c;
        float v = (Tt[i] - m) * rs * gg + bb;
        float x = fmaxf(X[i] + v, 0.f);
        X[i] = x;
        if (out) out[i] = x;
    }
}

// ---------- KPConv: one block per point ----------
// U[n,c] = sum_h ( sum_k infl[n,h,k]*Wk[k,c] ) * T[ref_idx[n,h], c]
// Influences recomputed per block into LDS (padded K=43 -> 44 for float4 reads).
__global__ __launch_bounds__(192) void k_kpconv(const float* __restrict__ coord,
                                               const int* __restrict__ ref_idx,
                                               const float* __restrict__ kp,
                                               const float* __restrict__ Wk,
                                               const float* __restrict__ T,
                                               float* __restrict__ U) {
    __shared__ float nb_s[NH][3];
    __shared__ int idx_s[NH];
    __shared__ __align__(16) float infl_s[NH * 44];

    const int n = blockIdx.x;
    const int tid = threadIdx.x;

    if (tid < NH) {
        int id = ref_idx[n * NH + tid];
        idx_s[tid] = id;
        float cx = coord[n * 3 + 0];
        float cy = coord[n * 3 + 1];
        float cz = coord[n * 3 + 2];
        nb_s[tid][0] = coord[id * 3 + 0] - cx;
        nb_s[tid][1] = coord[id * 3 + 1] - cy;
        nb_s[tid][2] = coord[id * 3 + 2] - cz;
        infl_s[tid * 44 + 43] = 0.f;   // zero the pad lane
    }
    __syncthreads();

    for (int t = tid; t < NH * NK; t += 192) {
        int h = t / NK;
        int k = t - h * NK;
        float dx = nb_s[h][0] - kp[k * 3 + 0];
        float dy = nb_s[h][1] - kp[k * 3 + 1];
        float dz = nb_s[h][2] - kp[k * 3 + 2];
        float d = sqrtf(fmaf(dx, dx, fmaf(dy, dy, dz * dz)));
        infl_s[h * 44 + k] = fmaxf(1.f - d, 0.f);   // SIGMA = 1
    }
    __syncthreads();

    const int c = tid;
    float wkr[44];
#pragma unroll
    for (int k = 0; k < NK; ++k) wkr[k] = Wk[k * NC + c];
    wkr[43] = 0.f;

    float gv[NH];
#pragma unroll
    for (int h = 0; h < NH; ++h) gv[h] = T[idx_s[h] * NC + c];  // gather, coalesced in c

    float acc = 0.f;
#pragma unroll
    for (int h = 0; h < NH; ++h) {
        const float4* ip = (const float4*)(infl_s + h * 44);
        float a = 0.f;
#pragma unroll
        for (int q = 0; q < 11; ++q) {
            float4 iv = ip[q];   // LDS broadcast (same addr all lanes)
            a = fmaf(iv.x, wkr[4 * q + 0], a);
            a = fmaf(iv.y, wkr[4 * q + 1], a);
            a = fmaf(iv.z, wkr[4 * q + 2], a);
            a = fmaf(iv.w, wkr[4 * q + 3], a);
        }
        acc = fmaf(a, gv[h], acc);
    }
    U[n * NC + c] = acc;
}

extern "C" void kernel_launch(void* const* d_in, const int* in_sizes, int n_in,
                              void* d_out, int out_size, void* d_ws, size_t ws_size,
                              hipStream_t stream) {
    const float* coord = (const float*)d_in[0];
    const float* feat  = (const float*)d_in[1];
    const int*   ridx  = (const int*)d_in[2];
    const float* kp    = (const float*)d_in[3];
    const float* W1    = (const float*)d_in[4];
    const float* Wk    = (const float*)d_in[5];
    const float* W3    = (const float*)d_in[6];
    const float* g1    = (const float*)d_in[7];
    const float* b1    = (const float*)d_in[8];
    const float* g2    = (const float*)d_in[9];
    const float* b2    = (const float*)d_in[10];
    const float* g3    = (const float*)d_in[11];
    const float* b3    = (const float*)d_in[12];
    float* out = (float*)d_out;

    // workspace layout (floats): X | T | U | part(64*2*C) | stats(2*C)  ~= 36.2 MB
    float* X     = (float*)d_ws;
    float* T     = X + N_PTS * NC;
    float* U     = T + N_PTS * NC;
    float* part  = U + N_PTS * NC;
    float* stats = part + 64 * 2 * NC;

    k_copy<<<2048, 256, 0, stream>>>(feat, X, N_PTS * NC);

    for (int d = 0; d < ND; ++d) {
        const float* W1d = W1 + d * NC * NC;
        const float* Wkd = Wk + d * NK * NC;
        const float* W3d = W3 + d * NC * NC;

        // fc1 + BN + ReLU
        k_gemm<<<N_PTS / 16, NC, 0, stream>>>(X, W1d, T);
        k_stat1<<<64, NC, 0, stream>>>(T, part);
        k_stat2<<<1, NC, 0, stream>>>(part, stats);
        k_bn_relu<<<N_PTS / 8, NC, 0, stream>>>(T, stats, g1 + d * NC, b1 + d * NC);

        // KPConvD + BN + ReLU
        k_kpconv<<<N_PTS, NC, 0, stream>>>(coord, ridx, kp, Wkd, T, U);
        k_stat1<<<64, NC, 0, stream>>>(U, part);
        k_stat2<<<1, NC, 0, stream>>>(part, stats);
        k_bn_relu<<<N_PTS / 8, NC, 0, stream>>>(U, stats, g2 + d * NC, b2 + d * NC);

        // fc3 + BN, skip + ReLU
        k_gemm<<<N_PTS / 16, NC, 0, stream>>>(U, W3d, T);
        k_stat1<<<64, NC, 0, stream>>>(T, part);
        k_stat2<<<1, NC, 0, stream>>>(part, stats);
        k_bn_skip<<<N_PTS / 8, NC, 0, stream>>>(T, stats, g3 + d * NC, b3 + d * NC, X,
                                                (d == ND - 1) ? out : (float*)nullptr);
    }
}